// Round 7
// baseline (247.746 us; speedup 1.0000x reference)
//
#include <hip/hip_runtime.h>
#include <hip/hip_bf16.h>

// Cholesky-QR formulation of classical Gram-Schmidt — zero-LDS version.
// 16 vectors x dim-256 per row, 32768 rows, fp32, layout (16, 32768, 256).
//
// G = V V^T via mfma_f32_16x16x32_bf16 (hi/lo split, 3 terms); L = chol(G)
// fused with forward substitution Q = L^{-1} V. CGS coefficients == L
// entries, so output matches the reference CGS bit-for-nearly.
//
// R6 changes vs R5 (which was LDS-capped at 2 waves/SIMD):
//  - MFMA fragments are loaded DIRECTLY from global (lane l reads 8-float
//    chunks of vector l&15; lines are L1/L2-hot from the coalesced v-load).
//    bf16 hi/lo split done in registers. LDS staging buffers deleted.
//  - G redistributed with 16 __shfl ops instead of LDS scatter/gather.
//    a[n] = shfl(g[n&3], vec + 16*(n>>2)) == G[vec][n] under either C/D
//    orientation (G symmetric).
//  - __launch_bounds__(64, 4): VGPR <= 128 -> 4 waves/SIMD, 2x residency.

constexpr int NM = 16;      // vectors per row
constexpr int NR = 32768;   // rows
constexpr int D4 = 64;      // float4 per vector

typedef __attribute__((ext_vector_type(8))) short short8v;  // 8 x bf16
typedef __attribute__((ext_vector_type(4))) float f32x4;

__device__ __forceinline__ float rl(float x, int lane) {
    return __builtin_bit_cast(float,
        __builtin_amdgcn_readlane(__builtin_bit_cast(int, x), lane));
}

__device__ __forceinline__ short bfbits(float f) {
    return __builtin_bit_cast(short, __float2bfloat16(f));
}

__global__ __launch_bounds__(64, 4) void gs_kernel(const float* __restrict__ x,
                                                   float* __restrict__ out) {
    const int lane = threadIdx.x;
    const int row  = blockIdx.x;
    const int vec  = lane & 15;   // vector owned in the MFMA fragment
    const int kgrp = lane >> 4;   // k-group 0..3

    const float4* __restrict__ xi = reinterpret_cast<const float4*>(x);
    float4* __restrict__ oo       = reinterpret_cast<float4*>(out);

    // Coalesced main load: lane l owns elements [4l, 4l+4) of every vector.
    float4 v[NM];
#pragma unroll
    for (int i = 0; i < NM; ++i)
        v[i] = xi[(size_t)(i * NR + row) * D4 + lane];

    // G = V V^T via MFMA; fragments re-read from global (cache-hot lines).
    // Frag for lane l, step c: floats [c*32 + kgrp*8, +8) of vector `vec`.
    const float4* __restrict__ fbase = xi + (size_t)(vec * NR + row) * D4;
    f32x4 g = {0.0f, 0.0f, 0.0f, 0.0f};
#pragma unroll
    for (int c = 0; c < 8; ++c) {
        float4 f0 = fbase[c * 8 + kgrp * 2];
        float4 f1 = fbase[c * 8 + kgrp * 2 + 1];
        float f[8] = {f0.x, f0.y, f0.z, f0.w, f1.x, f1.y, f1.z, f1.w};
        short8v ah, al;
#pragma unroll
        for (int j = 0; j < 8; ++j) {
            short hb = bfbits(f[j]);
            ah[j] = hb;
            float hv = __bfloat162float(__builtin_bit_cast(__hip_bfloat16, hb));
            al[j] = bfbits(f[j] - hv);
        }
        g = __builtin_amdgcn_mfma_f32_16x16x32_bf16(ah, ah, g, 0, 0, 0);
        g = __builtin_amdgcn_mfma_f32_16x16x32_bf16(ah, al, g, 0, 0, 0);
        g = __builtin_amdgcn_mfma_f32_16x16x32_bf16(al, ah, g, 0, 0, 0);
    }

    // Redistribute: a[n] = G[vec][n] via cross-lane shfl (no LDS, no barrier).
    // C/D map: lane m, reg r -> G[(m>>4)*4 + r][m&15]; with G symmetric the
    // same formula is valid under the transposed orientation too.
    float a[NM];
#pragma unroll
    for (int n = 0; n < NM; ++n)
        a[n] = __shfl(g[n & 3], vec + 16 * (n >> 2), 64);

    // Fused right-looking Cholesky + forward substitution (pure FMA chain).
#pragma unroll
    for (int j = 0; j < NM; ++j) {
        float p   = rl(a[j], j);                    // pivot = ||w_j||^2
        float inv = (p > 0.0f) ? rsqrtf(p) : 0.0f;  // safe-div
        v[j].x *= inv; v[j].y *= inv; v[j].z *= inv; v[j].w *= inv;   // q_j
        oo[(size_t)(j * NR + row) * D4 + lane] = v[j];
        a[j] *= inv;                                // column j of L
#pragma unroll
        for (int t = j + 1; t < NM; ++t) {
            float u = rl(a[j], t);                  // L[t][j] = <v_t, q_j>
            a[t]  = fmaf(-u, a[j], a[t]);           // Cholesky trailing update
            v[t].x = fmaf(-u, v[j].x, v[t].x);      // v_t -= L[t][j] * q_j
            v[t].y = fmaf(-u, v[j].y, v[t].y);
            v[t].z = fmaf(-u, v[j].z, v[t].z);
            v[t].w = fmaf(-u, v[j].w, v[t].w);
        }
    }
}

extern "C" void kernel_launch(void* const* d_in, const int* in_sizes, int n_in,
                              void* d_out, int out_size, void* d_ws, size_t ws_size,
                              hipStream_t stream) {
    const float* x = (const float*)d_in[0];
    float* out     = (float*)d_out;
    dim3 grid(NR);     // one wave per row
    dim3 block(64);
    hipLaunchKernelGGL(gs_kernel, grid, block, 0, stream, x, out);
}

// Round 9
// 222.338 us; speedup vs baseline: 1.1143x; 1.1143x over previous
//
#include <hip/hip_runtime.h>
#include <hip/hip_bf16.h>

// Cholesky-QR formulation of classical Gram-Schmidt.
// 16 vectors x dim-256 per row, 32768 rows, fp32, layout (16, 32768, 256).
//
// G = V V^T via mfma_f32_16x16x32_bf16 (hi/lo split, 3 terms); L = chol(G)
// fused with forward substitution Q = L^{-1} V (== CGS output).
//
// R8 changes vs R5 (18.2 KB LDS -> 2 waves/SIMD) and R7 (LDS sizing bug):
//  - k-split double-pass staging: phase p stages fp32 elements
//    [128p, 128p+128) of all 16 vectors (16 x 132 floats = 8448 B), runs
//    MFMA c-steps 4p..4p+3, then restages. Phase-p data lives in lanes
//    32p..32p+31's own registers -> half-exec ds_write_b128, no shuffles.
//    With 1 wave/block the extra __syncthreads are ~free.
//  - bf16 hi/lo conversion at frag-read time (same total convert ops).
//  - G redistribution via 16 __shfl (proven in R6), Cholesky core unchanged.
//  - __launch_bounds__(64, 4): target 4 waves/SIMD, ~2x R5 residency.

constexpr int NM   = 16;     // vectors per row
constexpr int NR   = 32768;  // rows
constexpr int D4   = 64;     // float4 per vector
constexpr int FROW = 132;    // floats per LDS row: 128 data + 4 pad

typedef __attribute__((ext_vector_type(8))) short short8v;  // 8 x bf16
typedef __attribute__((ext_vector_type(4))) float f32x4;

__device__ __forceinline__ float rl(float x, int lane) {
    return __builtin_bit_cast(float,
        __builtin_amdgcn_readlane(__builtin_bit_cast(int, x), lane));
}

// 8 fp32 -> bf16 hi + bf16 lo fragments (hi = bf16(f), lo = bf16(f - hi)).
__device__ __forceinline__ void cvt8(const float4& f0, const float4& f1,
                                     short8v& ah, short8v& al) {
    float f[8] = {f0.x, f0.y, f0.z, f0.w, f1.x, f1.y, f1.z, f1.w};
#pragma unroll
    for (int j = 0; j < 8; ++j) {
        unsigned short hb =
            __builtin_bit_cast(unsigned short, __float2bfloat16(f[j]));
        ah[j] = (short)hb;
        float hv = __builtin_bit_cast(float, (unsigned int)hb << 16);  // exact
        al[j] = (short)__builtin_bit_cast(unsigned short,
                                          __float2bfloat16(f[j] - hv));
    }
}

__global__ __launch_bounds__(64, 4) void gs_kernel(const float* __restrict__ x,
                                                   float* __restrict__ out) {
    __shared__ __align__(16) float sm[NM * FROW];   // 8448 B

    const int lane = threadIdx.x;
    const int row  = blockIdx.x;
    const int vec  = lane & 15;   // vector owned in the MFMA fragment
    const int kgrp = lane >> 4;   // k-group 0..3

    const float4* __restrict__ xi = reinterpret_cast<const float4*>(x);
    float4* __restrict__ oo       = reinterpret_cast<float4*>(out);

    // Coalesced load: lane l owns elements [4l, 4l+4) of every vector.
    float4 v[NM];
#pragma unroll
    for (int i = 0; i < NM; ++i)
        v[i] = xi[(size_t)(i * NR + row) * D4 + lane];

    // G = V V^T via MFMA, two k-phases through one half-size LDS buffer.
    f32x4 g = {0.0f, 0.0f, 0.0f, 0.0f};
#pragma unroll
    for (int p = 0; p < 2; ++p) {
        if (p) __syncthreads();   // prior phase's reads done before restage
        // Stage elements [128p, 128p+128): held by lanes 32p..32p+31.
        if ((lane >> 5) == p) {
            const int sl = lane & 31;
#pragma unroll
            for (int i = 0; i < NM; ++i)
                *reinterpret_cast<float4*>(&sm[i * FROW + 4 * sl]) = v[i];
        }
        __syncthreads();
        // MFMA c-steps over this phase's 128 elements.
#pragma unroll
        for (int c4 = 0; c4 < 4; ++c4) {
            const int off = vec * FROW + c4 * 32 + kgrp * 8;
            float4 f0 = *reinterpret_cast<const float4*>(&sm[off]);
            float4 f1 = *reinterpret_cast<const float4*>(&sm[off + 4]);
            short8v ah, al;
            cvt8(f0, f1, ah, al);
            g = __builtin_amdgcn_mfma_f32_16x16x32_bf16(ah, ah, g, 0, 0, 0);
            g = __builtin_amdgcn_mfma_f32_16x16x32_bf16(ah, al, g, 0, 0, 0);
            g = __builtin_amdgcn_mfma_f32_16x16x32_bf16(al, ah, g, 0, 0, 0);
        }
    }

    // Redistribute: a[n] = G[vec][n] via shfl. C/D map: lane m, reg r ->
    // G[(m>>4)*4 + r][m&15]; G symmetric -> orientation-proof.
    float a[NM];
#pragma unroll
    for (int n = 0; n < NM; ++n)
        a[n] = __shfl(g[n & 3], vec + 16 * (n >> 2), 64);

    // Fused right-looking Cholesky + forward substitution (pure FMA chain).
#pragma unroll
    for (int j = 0; j < NM; ++j) {
        float p   = rl(a[j], j);                    // pivot = ||w_j||^2
        float inv = (p > 0.0f) ? rsqrtf(p) : 0.0f;  // safe-div
        v[j].x *= inv; v[j].y *= inv; v[j].z *= inv; v[j].w *= inv;   // q_j
        oo[(size_t)(j * NR + row) * D4 + lane] = v[j];
        a[j] *= inv;                                // column j of L
#pragma unroll
        for (int t = j + 1; t < NM; ++t) {
            float u = rl(a[j], t);                  // L[t][j] = <v_t, q_j>
            a[t]  = fmaf(-u, a[j], a[t]);           // Cholesky trailing update
            v[t].x = fmaf(-u, v[j].x, v[t].x);      // v_t -= L[t][j] * q_j
            v[t].y = fmaf(-u, v[j].y, v[t].y);
            v[t].z = fmaf(-u, v[j].z, v[t].z);
            v[t].w = fmaf(-u, v[j].w, v[t].w);
        }
    }
}

extern "C" void kernel_launch(void* const* d_in, const int* in_sizes, int n_in,
                              void* d_out, int out_size, void* d_ws, size_t ws_size,
                              hipStream_t stream) {
    const float* x = (const float*)d_in[0];
    float* out     = (float*)d_out;
    dim3 grid(NR);     // one wave per row
    dim3 block(64);
    hipLaunchKernelGGL(gs_kernel, grid, block, 0, stream, x, out);
}